// Round 14
// baseline (472.074 us; speedup 1.0000x reference)
//
#include <hip/hip_runtime.h>
#include <math.h>

#define LN2F 0.6931471805599453f
#define LOG2EF 1.4426950408889634f

typedef _Float16 half_t;
typedef _Float16 half4_t __attribute__((ext_vector_type(4)));
typedef _Float16 half8_t __attribute__((ext_vector_type(8)));
typedef __fp16 fp16x2 __attribute__((ext_vector_type(2)));
typedef __fp16 fp16x4 __attribute__((ext_vector_type(4)));
typedef __fp16 fp16x8 __attribute__((ext_vector_type(8)));
typedef float f32x4 __attribute__((ext_vector_type(4)));

__device__ __forceinline__ float sspf(float z) {   // safe version (node MLP)
    return fmaxf(z, 0.f) + __logf(1.f + __expf(-fabsf(z))) - LN2F;
}
__device__ __forceinline__ half4_t cvt4(float x, float y, float z, float w) {
    half4_t r; r[0]=(half_t)x; r[1]=(half_t)y; r[2]=(half_t)z; r[3]=(half_t)w; return r;
}
// pack 8 floats to half8 via v_cvt_pkrtz_f16_f32 (4 instrs)
__device__ __forceinline__ half8_t pk8(float a, float b, float c, float d,
                                       float e, float f, float g, float h) {
    fp16x2 p0 = __builtin_amdgcn_cvt_pkrtz(a, b);
    fp16x2 p1 = __builtin_amdgcn_cvt_pkrtz(c, d);
    fp16x2 p2 = __builtin_amdgcn_cvt_pkrtz(e, f);
    fp16x2 p3 = __builtin_amdgcn_cvt_pkrtz(g, h);
    fp16x4 lo = __builtin_shufflevector(p0, p1, 0, 1, 2, 3);
    fp16x4 hi = __builtin_shufflevector(p2, p3, 0, 1, 2, 3);
    fp16x8 v  = __builtin_shufflevector(lo, hi, 0, 1, 2, 3, 4, 5, 6, 7);
    return __builtin_bit_cast(half8_t, v);
}

__device__ __forceinline__ int lbound(const int* __restrict__ a, int n, int key) {
    int lo = 0, hi = n;
    while (lo < hi) { int m = (lo + hi) >> 1; if (a[m] < key) lo = m + 1; else hi = m; }
    return lo;
}

// Weight prep (layouts validated R12/R13).
//  Wt_in2f/Wt_o1/Wt_o2: dst[n*128+k] = W[k][n]  (f16)
//  Wt_f1: dst[n*32+k] = W_f1[k][n], k<20 else 0   (x32 A-frags, K-padded)
//  W2L (x32-stacked, pre-scaled by ln2; out-col = ln*8 + nt):
//    flat i: j=i&7, ln=(i>>3)&15, g=(i>>7)&3, nt=(i>>9)&7, t=i>>12
//    k = 32t + (j<4 ? g*4+j : 16+g*4+(j-4))
//    W2L[i] = ln2 * W_f2[k*128 + ln*8 + nt]
//  b1sc = b_f1*log2e ; b2a = b_f2 - ln2*colsum(W_f2)
__global__ __launch_bounds__(256) void prep_weights(
    const float* __restrict__ W_in2f, const float* __restrict__ W_f1,
    const float* __restrict__ W_f2, const float* __restrict__ W_o1,
    const float* __restrict__ W_o2,
    const float* __restrict__ b_f1, const float* __restrict__ b_f2,
    half_t* __restrict__ Wt_in2f, half_t* __restrict__ Wt_f1,
    half_t* __restrict__ W2L, half_t* __restrict__ Wt_o1,
    half_t* __restrict__ Wt_o2, float* __restrict__ b1sc, float* __restrict__ b2a)
{
    int b = blockIdx.x;
    if (b < 64) {
        int i = b*256 + threadIdx.x;
        Wt_in2f[i] = (half_t)W_in2f[(i & 127)*128 + (i >> 7)];
    } else if (b < 80) {
        int i = (b-64)*256 + threadIdx.x;
        int n = i >> 5, k = i & 31;
        Wt_f1[i] = (k < 20) ? (half_t)W_f1[k*128 + n] : (half_t)0.f;
    } else if (b < 144) {
        int i = (b-80)*256 + threadIdx.x;     // 0..16383
        int j = i & 7, ln = (i >> 3) & 15, g = (i >> 7) & 3;
        int nt = (i >> 9) & 7, t = i >> 12;
        int k = 32*t + ((j < 4) ? (g*4 + j) : (16 + g*4 + (j - 4)));
        W2L[i] = (half_t)(LN2F * W_f2[k*128 + ln*8 + nt]);
    } else if (b < 208) {
        int i = (b-144)*256 + threadIdx.x;
        Wt_o1[i] = (half_t)W_o1[(i & 127)*128 + (i >> 7)];
    } else if (b < 272) {
        int i = (b-208)*256 + threadIdx.x;
        Wt_o2[i] = (half_t)W_o2[(i & 127)*128 + (i >> 7)];
    } else {
        int c = threadIdx.x;
        if (c < 128) {
            float s = 0.f;
            for (int k = 0; k < 128; ++k) s += W_f2[k*128 + c];
            b2a[c]  = b_f2[c] - LN2F * s;
            b1sc[c] = b_f1[c] * LOG2EF;
        }
    }
}

// atom_start[a] = first edge index with idx_i >= a; atom_start[N] = E
__global__ __launch_bounds__(256) void seg_starts(
    const int* __restrict__ idx_i, int* __restrict__ atom_start, int E, int N)
{
    int e = blockIdx.x * 256 + threadIdx.x;
    if (e >= E) return;
    int a = idx_i[e];
    int prev = (e == 0) ? -1 : idx_i[e - 1];
    for (int k = prev + 1; k <= a; ++k) atom_start[k] = e;
    if (e == E - 1)
        for (int k = a + 1; k <= N; ++k) atom_start[k] = E;
}

// h = x @ W_in2f -> f16
__global__ __launch_bounds__(256) void mfma_gemm_h(
    const float* __restrict__ A, const half_t* __restrict__ Bt,
    half_t* __restrict__ Ch, int nrows)
{
    const int tid = threadIdx.x;
    const int w = tid >> 6, l = tid & 63, g = l >> 4, ln = l & 15;
    const int r0 = blockIdx.x * 64;

    f32x4 acc[4][2];
    #pragma unroll
    for (int rf = 0; rf < 4; ++rf)
        #pragma unroll
        for (int cf = 0; cf < 2; ++cf) acc[rf][cf] = (f32x4)0.f;

    #pragma unroll
    for (int kk = 0; kk < 8; ++kk) {
        const int kb = kk * 16 + g * 4;
        half4_t a[4];
        #pragma unroll
        for (int rf = 0; rf < 4; ++rf) {
            int r = r0 + rf * 16 + ln;
            int rr = r < nrows ? r : nrows - 1;
            float4 av = *(const float4*)(A + (size_t)rr * 128 + kb);
            a[rf] = cvt4(av.x, av.y, av.z, av.w);
        }
        #pragma unroll
        for (int cf = 0; cf < 2; ++cf) {
            int n = w * 32 + cf * 16 + ln;
            half4_t b = *(const half4_t*)(Bt + (size_t)n * 128 + kb);
            #pragma unroll
            for (int rf = 0; rf < 4; ++rf)
                acc[rf][cf] = __builtin_amdgcn_mfma_f32_16x16x16f16(a[rf], b, acc[rf][cf], 0, 0, 0);
        }
    }
    #pragma unroll
    for (int cf = 0; cf < 2; ++cf) {
        int n = w * 32 + cf * 16 + ln;
        #pragma unroll
        for (int rf = 0; rf < 4; ++rf)
            #pragma unroll
            for (int reg = 0; reg < 4; ++reg) {
                int r = r0 + rf * 16 + g * 4 + reg;
                if (r < nrows) Ch[(size_t)r * 128 + n] = (half_t)acc[rf][cf][reg];
            }
    }
}

// fused out-MLP: out = ssp(agg@O1+b1)@O2+b2  (t staged in LDS f16)
__global__ __launch_bounds__(256) void mfma_gemm2(
    const float* __restrict__ A, const half_t* __restrict__ Bt1,
    const float* __restrict__ bias1, const half_t* __restrict__ Bt2,
    const float* __restrict__ bias2, float* __restrict__ out, int nrows)
{
    __shared__ half_t ts[64][136];
    const int tid = threadIdx.x;
    const int w = tid >> 6, l = tid & 63, g = l >> 4, ln = l & 15;
    const int r0 = blockIdx.x * 64;

    // layer 1
    f32x4 acc[4][2];
    #pragma unroll
    for (int rf = 0; rf < 4; ++rf)
        #pragma unroll
        for (int cf = 0; cf < 2; ++cf) acc[rf][cf] = (f32x4)0.f;
    #pragma unroll
    for (int kk = 0; kk < 8; ++kk) {
        const int kb = kk * 16 + g * 4;
        half4_t a[4];
        #pragma unroll
        for (int rf = 0; rf < 4; ++rf) {
            int r = r0 + rf * 16 + ln;
            int rr = r < nrows ? r : nrows - 1;
            float4 av = *(const float4*)(A + (size_t)rr * 128 + kb);
            a[rf] = cvt4(av.x, av.y, av.z, av.w);
        }
        #pragma unroll
        for (int cf = 0; cf < 2; ++cf) {
            int n = w * 32 + cf * 16 + ln;
            half4_t b = *(const half4_t*)(Bt1 + (size_t)n * 128 + kb);
            #pragma unroll
            for (int rf = 0; rf < 4; ++rf)
                acc[rf][cf] = __builtin_amdgcn_mfma_f32_16x16x16f16(a[rf], b, acc[rf][cf], 0, 0, 0);
        }
    }
    #pragma unroll
    for (int cf = 0; cf < 2; ++cf) {
        int n = w * 32 + cf * 16 + ln;
        float bv = bias1[n];
        #pragma unroll
        for (int rf = 0; rf < 4; ++rf)
            #pragma unroll
            for (int reg = 0; reg < 4; ++reg)
                ts[rf*16 + g*4 + reg][n] = (half_t)sspf(acc[rf][cf][reg] + bv);
    }
    __syncthreads();

    // layer 2
    f32x4 acc2[4][2];
    #pragma unroll
    for (int rf = 0; rf < 4; ++rf)
        #pragma unroll
        for (int cf = 0; cf < 2; ++cf) acc2[rf][cf] = (f32x4)0.f;
    #pragma unroll
    for (int kk = 0; kk < 8; ++kk) {
        const int kb = kk * 16 + g * 4;
        half4_t a[4];
        #pragma unroll
        for (int rf = 0; rf < 4; ++rf)
            a[rf] = *(const half4_t*)&ts[rf*16 + ln][kb];
        #pragma unroll
        for (int cf = 0; cf < 2; ++cf) {
            int n = w * 32 + cf * 16 + ln;
            half4_t b = *(const half4_t*)(Bt2 + (size_t)n * 128 + kb);
            #pragma unroll
            for (int rf = 0; rf < 4; ++rf)
                acc2[rf][cf] = __builtin_amdgcn_mfma_f32_16x16x16f16(a[rf], b, acc2[rf][cf], 0, 0, 0);
        }
    }
    #pragma unroll
    for (int cf = 0; cf < 2; ++cf) {
        int n = w * 32 + cf * 16 + ln;
        float bv = bias2[n];
        #pragma unroll
        for (int rf = 0; rf < 4; ++rf)
            #pragma unroll
            for (int reg = 0; reg < 4; ++reg) {
                int r = r0 + rf * 16 + g * 4 + reg;
                if (r < nrows) out[(size_t)r * 128 + n] = acc2[rf][cf][reg] + bv;
            }
    }
}

// Wave-independent edge pipeline, R14: h in REGISTERS (coalesced dwordx4 per
// 16-lane group), no hsh LDS -> 4 blocks/CU (4 waves/SIMD). Pure 1-ahead
// prefetch; conservative vmcnt(4) retires h while keeping >=1 prefetch load
// in flight regardless of compiler load merging.
__global__ __launch_bounds__(256, 4) void edge_kernel(
    const float* __restrict__ f_ij, const float* __restrict__ rcut,
    const int* __restrict__ idx_j,
    const half_t* __restrict__ Wt_f1, const float* __restrict__ b1sc,
    const half_t* __restrict__ W2L, const float* __restrict__ b2a,
    const half_t* __restrict__ hh, float* __restrict__ agg,
    const int* __restrict__ atom_start, int E, int N, int W)
{
    __shared__ __align__(16) half_t W2s[16384];        // 32768 B
    __shared__ float b1s[128];                         //   512 B
    // 33280 B -> 4 blocks/CU

    const int tid = threadIdx.x;
    const int w = tid >> 6, l = tid & 63, g = l >> 4, ln = l & 15;

    for (int i = tid; i < 2048; i += 256)
        ((float4*)W2s)[i] = ((const float4*)W2L)[i];
    if (tid < 128) b1s[tid] = b1sc[tid];
    __syncthreads();

    // per-wave atom range (edge-balanced)
    const int kg = blockIdx.x * 4 + w;
    const int aLo = lbound(atom_start, N + 1, (int)((size_t)kg * E / W));
    const int aHi = (kg == W - 1) ? N
                  : lbound(atom_start, N + 1, (int)((size_t)(kg + 1) * E / W));
    if (aLo >= aHi) return;

    // W1 A-frags in VGPRs (x32 stacked-K)
    half8_t w1f[8];
    #pragma unroll
    for (int rf = 0; rf < 8; ++rf) {
        half4_t lo = *(const half4_t*)(Wt_f1 + (size_t)(rf*16 + ln)*32 + g*4);
        half4_t hi = *(const half4_t*)(Wt_f1 + (size_t)(rf*16 + ln)*32 + 16 + g*4);
        w1f[rf] = __builtin_shufflevector(lo, hi, 0, 1, 2, 3, 4, 5, 6, 7);
    }

    // persistent b2' accumulator seeds (lane cols = ln*8 .. ln*8+7)
    f32x4 b2acc[8];
    {
        float4 blo4 = *(const float4*)(b2a + ln*8);
        float4 bhi4 = *(const float4*)(b2a + ln*8 + 4);
        float bv[8] = {blo4.x, blo4.y, blo4.z, blo4.w, bhi4.x, bhi4.y, bhi4.z, bhi4.w};
        #pragma unroll
        for (int q = 0; q < 8; ++q) {
            f32x4 t = {bv[q], bv[q], bv[q], bv[q]};
            b2acc[q] = t;
        }
    }

    // atom window
    int acur = aLo;
    int ends0 = atom_start[acur + 1];
    int ends1 = atom_start[min(acur + 2, N)];
    int ends2 = atom_start[min(acur + 3, N)];
    int cs = atom_start[acur];

    // prologue: chunk-0 jv/f/rc (direct)
    int jv[4]; float4 fA, fB; float rc[4];
    #pragma unroll
    for (int r2 = 0; r2 < 4; ++r2)
        jv[r2] = idx_j[min(cs + 4*g + r2, E - 1)];
    {
        int e = min(cs + ln, E - 1);
        fA = *(const float4*)(f_ij + (size_t)e*20 + g*4);
        fB = *(const float4*)(f_ij + (size_t)e*20 + 16);
    }
    #pragma unroll
    for (int r2 = 0; r2 < 4; ++r2) rc[r2] = rcut[min(cs + 4*g + r2, E - 1)];
    asm volatile("" ::: "memory");

    float racc[8];
    #pragma unroll
    for (int q = 0; q < 8; ++q) racc[q] = 0.f;

    while (acur < aHi) {
        const int ce = min(cs + 16, ends0);
        const int csn = ce;
        const bool flushF = (ce == ends0);

        // ---- 1: h loads for CURRENT chunk (4x dwordx4, coalesced per group) ----
        float4 hpre[4];
        #pragma unroll
        for (int r2 = 0; r2 < 4; ++r2)
            hpre[r2] = *(const float4*)(hh + (size_t)jv[r2]*128 + ln*8);
        asm volatile("" ::: "memory");

        // ---- 2: consume prefetched f/rc ----
        half4_t blo = cvt4(fA.x, fA.y, fA.z, fA.w);
        half4_t bhi;
        if (g == 0) bhi = cvt4(fB.x, fB.y, fB.z, fB.w);
        else { half4_t zz = {}; bhi = zz; }
        half8_t bf = __builtin_shufflevector(blo, bhi, 0, 1, 2, 3, 4, 5, 6, 7);
        float rcm[4];
        #pragma unroll
        for (int r2 = 0; r2 < 4; ++r2)
            rcm[r2] = (cs + 4*g + r2 < ce) ? rc[r2] : 0.f;

        // ---- 3: prefetch NEXT chunk (jv/f/rc at csn) + atom window ----
        int jvn[4];
        #pragma unroll
        for (int r2 = 0; r2 < 4; ++r2)
            jvn[r2] = idx_j[min(csn + 4*g + r2, E - 1)];
        float4 fA1, fB1;
        {
            int e = min(csn + ln, E - 1);
            fA1 = *(const float4*)(f_ij + (size_t)e*20 + g*4);
            fB1 = *(const float4*)(f_ij + (size_t)e*20 + 16);
        }
        float rc1[4];
        #pragma unroll
        for (int r2 = 0; r2 < 4; ++r2) rc1[r2] = rcut[min(csn + 4*g + r2, E - 1)];
        const int aeL = atom_start[min(acur + 4, N)];
        asm volatile("" ::: "memory");

        // ---- 4: phase 1 (K=32) + folded softplus: a2 = log2(1 + 2^u) ----
        f32x4 z[8];
        #pragma unroll
        for (int rf = 0; rf < 8; ++rf)
            z[rf] = __builtin_amdgcn_mfma_f32_16x16x32_f16(w1f[rf], bf, (f32x4)0.f, 0, 0, 0);
        half8_t a2[4];
        #pragma unroll
        for (int t = 0; t < 4; ++t) {
            float4 bbA = *(const float4*)&b1s[(2*t)*16 + g*4];
            float4 bbB = *(const float4*)&b1s[(2*t+1)*16 + g*4];
            float l0 = __log2f(1.f + exp2f(fmaf(z[2*t][0],   LOG2EF, bbA.x)));
            float l1 = __log2f(1.f + exp2f(fmaf(z[2*t][1],   LOG2EF, bbA.y)));
            float l2 = __log2f(1.f + exp2f(fmaf(z[2*t][2],   LOG2EF, bbA.z)));
            float l3 = __log2f(1.f + exp2f(fmaf(z[2*t][3],   LOG2EF, bbA.w)));
            float l4 = __log2f(1.f + exp2f(fmaf(z[2*t+1][0], LOG2EF, bbB.x)));
            float l5 = __log2f(1.f + exp2f(fmaf(z[2*t+1][1], LOG2EF, bbB.y)));
            float l6 = __log2f(1.f + exp2f(fmaf(z[2*t+1][2], LOG2EF, bbB.z)));
            float l7 = __log2f(1.f + exp2f(fmaf(z[2*t+1][3], LOG2EF, bbB.w)));
            a2[t] = pk8(l0, l1, l2, l3, l4, l5, l6, l7);
        }

        // ---- 5: phase 2 (32 MFMA), acc seeded from persistent b2acc ----
        f32x4 acc[8];
        #pragma unroll
        for (int q = 0; q < 8; ++q) acc[q] = b2acc[q];
        __builtin_amdgcn_s_setprio(1);
        #pragma unroll
        for (int t = 0; t < 4; ++t)
            #pragma unroll
            for (int q = 0; q < 8; ++q) {
                half8_t bw = *(const half8_t*)&W2s[(((t*8 + q)*4 + g)*16 + ln)*8];
                acc[q] = __builtin_amdgcn_mfma_f32_16x16x32_f16(a2[t], bw, acc[q], 0, 0, 0);
            }
        __builtin_amdgcn_s_setprio(0);

        // ---- 6: retire h loads (conservative count; h are the oldest) ----
        asm volatile("s_waitcnt vmcnt(4)" ::: "memory");
        __builtin_amdgcn_sched_barrier(0);

        // ---- 7: epilogue from registers ----
        #pragma unroll
        for (int r2 = 0; r2 < 4; ++r2) {
            half8_t hv8 = __builtin_bit_cast(half8_t, hpre[r2]);
            float rr = rcm[r2];
            #pragma unroll
            for (int q = 0; q < 8; ++q)
                racc[q] = fmaf(acc[q][r2] * rr, (float)hv8[q], racc[q]);
        }

        // ---- 8: atom flush (coalesced float4 stores) ----
        if (flushF) {
            #pragma unroll
            for (int q = 0; q < 8; ++q) {
                float r = racc[q];
                r += __shfl_xor(r, 16, 64);
                r += __shfl_xor(r, 32, 64);
                racc[q] = r;
            }
            if (g == 0) {
                float4 v0 = {racc[0], racc[1], racc[2], racc[3]};
                float4 v1 = {racc[4], racc[5], racc[6], racc[7]};
                *(float4*)(agg + (size_t)acur*128 + ln*8)     = v0;
                *(float4*)(agg + (size_t)acur*128 + ln*8 + 4) = v1;
            }
            #pragma unroll
            for (int q = 0; q < 8; ++q) racc[q] = 0.f;
            ++acur;
            ends0 = ends1; ends1 = ends2; ends2 = aeL;
        }

        // ---- 9: rotate pipeline state ----
        cs = csn;
        #pragma unroll
        for (int r2 = 0; r2 < 4; ++r2) { jv[r2] = jvn[r2]; rc[r2] = rc1[r2]; }
        fA = fA1; fB = fB1;
    }
}

extern "C" void kernel_launch(void* const* d_in, const int* in_sizes, int n_in,
                              void* d_out, int out_size, void* d_ws, size_t ws_size,
                              hipStream_t stream)
{
    const float* x      = (const float*)d_in[0];
    const float* f_ij   = (const float*)d_in[1];
    const float* rcut   = (const float*)d_in[2];
    const int*   idx_i  = (const int*)d_in[3];
    const int*   idx_j  = (const int*)d_in[4];
    const float* W_in2f = (const float*)d_in[5];
    const float* W_f1   = (const float*)d_in[6];
    const float* b_f1   = (const float*)d_in[7];
    const float* W_f2   = (const float*)d_in[8];
    const float* b_f2   = (const float*)d_in[9];
    const float* W_o1   = (const float*)d_in[10];
    const float* b_o1   = (const float*)d_in[11];
    const float* W_o2   = (const float*)d_in[12];
    const float* b_o2   = (const float*)d_in[13];

    const int N = in_sizes[0] / 128;
    const int E = in_sizes[2];

    half_t* h16  = (half_t*)d_ws;                       // [N,128] f16
    half_t* wt   = (half_t*)((char*)d_ws + (size_t)N * 128 * 4);
    half_t* Wt_in2f = wt;                 // 16384 halfs
    half_t* Wt_f1   = wt + 16384;         //  4096 (x32-padded [n][32])
    half_t* W2L     = wt + 16384 + 4096;  // 16384 (x32 stacked W_f2 * ln2)
    half_t* Wt_o1   = W2L + 16384;        // 16384
    half_t* Wt_o2   = Wt_o1 + 16384;      // 16384
    float*  b1sc    = (float*)(Wt_o2 + 16384);          // 128 floats
    float*  b2a     = b1sc + 128;                       // 128 floats
    int* atom_start = (int*)(b2a + 128);                // N+1 ints

    prep_weights<<<273, 256, 0, stream>>>(W_in2f, W_f1, W_f2, W_o1, W_o2,
                                          b_f1, b_f2,
                                          Wt_in2f, Wt_f1, W2L, Wt_o1, Wt_o2,
                                          b1sc, b2a);
    seg_starts<<<(E + 255) / 256, 256, 0, stream>>>(idx_i, atom_start, E, N);

    const int gn  = (N + 63) / 64;
    const int nbl = 1024;                 // 4 waves/block, 4 blocks/CU
    const int W   = nbl * 4;

    // h = x @ W_in2f -> f16
    mfma_gemm_h<<<gn, 256, 0, stream>>>(x, Wt_in2f, h16, N);

    // wave-independent fused edge pipeline -> agg (writes every atom row once)
    edge_kernel<<<nbl, 256, 0, stream>>>(f_ij, rcut, idx_j,
                                         Wt_f1, b1sc, W2L, b2a,
                                         h16, (float*)d_out, atom_start, E, N, W);

    // out = ssp(agg @ W_o1 + b_o1) @ W_o2 + b_o2   (fused, in-place on d_out)
    mfma_gemm2<<<gn, 256, 0, stream>>>((const float*)d_out, Wt_o1, b_o1,
                                       Wt_o2, b_o2, (float*)d_out, N);
}

// Round 15
// 282.324 us; speedup vs baseline: 1.6721x; 1.6721x over previous
//
#include <hip/hip_runtime.h>
#include <math.h>

#define LN2F 0.6931471805599453f
#define LOG2EF 1.4426950408889634f

typedef _Float16 half_t;
typedef _Float16 half4_t __attribute__((ext_vector_type(4)));
typedef _Float16 half8_t __attribute__((ext_vector_type(8)));
typedef __fp16 fp16x2 __attribute__((ext_vector_type(2)));
typedef __fp16 fp16x4 __attribute__((ext_vector_type(4)));
typedef __fp16 fp16x8 __attribute__((ext_vector_type(8)));
typedef float f32x4 __attribute__((ext_vector_type(4)));

__device__ __forceinline__ float sspf(float z) {   // safe version (node MLP)
    return fmaxf(z, 0.f) + __logf(1.f + __expf(-fabsf(z))) - LN2F;
}
__device__ __forceinline__ half4_t cvt4(float x, float y, float z, float w) {
    half4_t r; r[0]=(half_t)x; r[1]=(half_t)y; r[2]=(half_t)z; r[3]=(half_t)w; return r;
}
// pack 8 floats to half8 via v_cvt_pkrtz_f16_f32 (4 instrs)
__device__ __forceinline__ half8_t pk8(float a, float b, float c, float d,
                                       float e, float f, float g, float h) {
    fp16x2 p0 = __builtin_amdgcn_cvt_pkrtz(a, b);
    fp16x2 p1 = __builtin_amdgcn_cvt_pkrtz(c, d);
    fp16x2 p2 = __builtin_amdgcn_cvt_pkrtz(e, f);
    fp16x2 p3 = __builtin_amdgcn_cvt_pkrtz(g, h);
    fp16x4 lo = __builtin_shufflevector(p0, p1, 0, 1, 2, 3);
    fp16x4 hi = __builtin_shufflevector(p2, p3, 0, 1, 2, 3);
    fp16x8 v  = __builtin_shufflevector(lo, hi, 0, 1, 2, 3, 4, 5, 6, 7);
    return __builtin_bit_cast(half8_t, v);
}

// async global->LDS DMA, 16 B per lane; dest = wave-uniform base + lane*16
__device__ __forceinline__ void load_lds16(const void* g, void* l) {
    __builtin_amdgcn_global_load_lds(
        (const __attribute__((address_space(1))) unsigned int*)g,
        (__attribute__((address_space(3))) unsigned int*)l, 16, 0, 0);
}

__device__ __forceinline__ int lbound(const int* __restrict__ a, int n, int key) {
    int lo = 0, hi = n;
    while (lo < hi) { int m = (lo + hi) >> 1; if (a[m] < key) lo = m + 1; else hi = m; }
    return lo;
}

// Weight prep (layouts validated R12/R13).
//  Wt_in2f/Wt_o1/Wt_o2: dst[n*128+k] = W[k][n]  (f16)
//  Wt_f1: dst[n*32+k] = W_f1[k][n], k<20 else 0   (x32 A-frags, K-padded)
//  W2L (x32-stacked, pre-scaled by ln2; out-col = ln*8 + nt):
//    flat i: j=i&7, ln=(i>>3)&15, g=(i>>7)&3, nt=(i>>9)&7, t=i>>12
//    k = 32t + (j<4 ? g*4+j : 16+g*4+(j-4))
//    W2L[i] = ln2 * W_f2[k*128 + ln*8 + nt]
//  b1sc = b_f1*log2e ; b2a = b_f2 - ln2*colsum(W_f2)
__global__ __launch_bounds__(256) void prep_weights(
    const float* __restrict__ W_in2f, const float* __restrict__ W_f1,
    const float* __restrict__ W_f2, const float* __restrict__ W_o1,
    const float* __restrict__ W_o2,
    const float* __restrict__ b_f1, const float* __restrict__ b_f2,
    half_t* __restrict__ Wt_in2f, half_t* __restrict__ Wt_f1,
    half_t* __restrict__ W2L, half_t* __restrict__ Wt_o1,
    half_t* __restrict__ Wt_o2, float* __restrict__ b1sc, float* __restrict__ b2a)
{
    int b = blockIdx.x;
    if (b < 64) {
        int i = b*256 + threadIdx.x;
        Wt_in2f[i] = (half_t)W_in2f[(i & 127)*128 + (i >> 7)];
    } else if (b < 80) {
        int i = (b-64)*256 + threadIdx.x;
        int n = i >> 5, k = i & 31;
        Wt_f1[i] = (k < 20) ? (half_t)W_f1[k*128 + n] : (half_t)0.f;
    } else if (b < 144) {
        int i = (b-80)*256 + threadIdx.x;     // 0..16383
        int j = i & 7, ln = (i >> 3) & 15, g = (i >> 7) & 3;
        int nt = (i >> 9) & 7, t = i >> 12;
        int k = 32*t + ((j < 4) ? (g*4 + j) : (16 + g*4 + (j - 4)));
        W2L[i] = (half_t)(LN2F * W_f2[k*128 + ln*8 + nt]);
    } else if (b < 208) {
        int i = (b-144)*256 + threadIdx.x;
        Wt_o1[i] = (half_t)W_o1[(i & 127)*128 + (i >> 7)];
    } else if (b < 272) {
        int i = (b-208)*256 + threadIdx.x;
        Wt_o2[i] = (half_t)W_o2[(i & 127)*128 + (i >> 7)];
    } else {
        int c = threadIdx.x;
        if (c < 128) {
            float s = 0.f;
            for (int k = 0; k < 128; ++k) s += W_f2[k*128 + c];
            b2a[c]  = b_f2[c] - LN2F * s;
            b1sc[c] = b_f1[c] * LOG2EF;
        }
    }
}

// atom_start[a] = first edge index with idx_i >= a; atom_start[N] = E
__global__ __launch_bounds__(256) void seg_starts(
    const int* __restrict__ idx_i, int* __restrict__ atom_start, int E, int N)
{
    int e = blockIdx.x * 256 + threadIdx.x;
    if (e >= E) return;
    int a = idx_i[e];
    int prev = (e == 0) ? -1 : idx_i[e - 1];
    for (int k = prev + 1; k <= a; ++k) atom_start[k] = e;
    if (e == E - 1)
        for (int k = a + 1; k <= N; ++k) atom_start[k] = E;
}

// h = x @ W_in2f -> f16
__global__ __launch_bounds__(256) void mfma_gemm_h(
    const float* __restrict__ A, const half_t* __restrict__ Bt,
    half_t* __restrict__ Ch, int nrows)
{
    const int tid = threadIdx.x;
    const int w = tid >> 6, l = tid & 63, g = l >> 4, ln = l & 15;
    const int r0 = blockIdx.x * 64;

    f32x4 acc[4][2];
    #pragma unroll
    for (int rf = 0; rf < 4; ++rf)
        #pragma unroll
        for (int cf = 0; cf < 2; ++cf) acc[rf][cf] = (f32x4)0.f;

    #pragma unroll
    for (int kk = 0; kk < 8; ++kk) {
        const int kb = kk * 16 + g * 4;
        half4_t a[4];
        #pragma unroll
        for (int rf = 0; rf < 4; ++rf) {
            int r = r0 + rf * 16 + ln;
            int rr = r < nrows ? r : nrows - 1;
            float4 av = *(const float4*)(A + (size_t)rr * 128 + kb);
            a[rf] = cvt4(av.x, av.y, av.z, av.w);
        }
        #pragma unroll
        for (int cf = 0; cf < 2; ++cf) {
            int n = w * 32 + cf * 16 + ln;
            half4_t b = *(const half4_t*)(Bt + (size_t)n * 128 + kb);
            #pragma unroll
            for (int rf = 0; rf < 4; ++rf)
                acc[rf][cf] = __builtin_amdgcn_mfma_f32_16x16x16f16(a[rf], b, acc[rf][cf], 0, 0, 0);
        }
    }
    #pragma unroll
    for (int cf = 0; cf < 2; ++cf) {
        int n = w * 32 + cf * 16 + ln;
        #pragma unroll
        for (int rf = 0; rf < 4; ++rf)
            #pragma unroll
            for (int reg = 0; reg < 4; ++reg) {
                int r = r0 + rf * 16 + g * 4 + reg;
                if (r < nrows) Ch[(size_t)r * 128 + n] = (half_t)acc[rf][cf][reg];
            }
    }
}

// fused out-MLP: out = ssp(agg@O1+b1)@O2+b2  (t staged in LDS f16)
__global__ __launch_bounds__(256) void mfma_gemm2(
    const float* __restrict__ A, const half_t* __restrict__ Bt1,
    const float* __restrict__ bias1, const half_t* __restrict__ Bt2,
    const float* __restrict__ bias2, float* __restrict__ out, int nrows)
{
    __shared__ half_t ts[64][136];
    const int tid = threadIdx.x;
    const int w = tid >> 6, l = tid & 63, g = l >> 4, ln = l & 15;
    const int r0 = blockIdx.x * 64;

    // layer 1
    f32x4 acc[4][2];
    #pragma unroll
    for (int rf = 0; rf < 4; ++rf)
        #pragma unroll
        for (int cf = 0; cf < 2; ++cf) acc[rf][cf] = (f32x4)0.f;
    #pragma unroll
    for (int kk = 0; kk < 8; ++kk) {
        const int kb = kk * 16 + g * 4;
        half4_t a[4];
        #pragma unroll
        for (int rf = 0; rf < 4; ++rf) {
            int r = r0 + rf * 16 + ln;
            int rr = r < nrows ? r : nrows - 1;
            float4 av = *(const float4*)(A + (size_t)rr * 128 + kb);
            a[rf] = cvt4(av.x, av.y, av.z, av.w);
        }
        #pragma unroll
        for (int cf = 0; cf < 2; ++cf) {
            int n = w * 32 + cf * 16 + ln;
            half4_t b = *(const half4_t*)(Bt1 + (size_t)n * 128 + kb);
            #pragma unroll
            for (int rf = 0; rf < 4; ++rf)
                acc[rf][cf] = __builtin_amdgcn_mfma_f32_16x16x16f16(a[rf], b, acc[rf][cf], 0, 0, 0);
        }
    }
    #pragma unroll
    for (int cf = 0; cf < 2; ++cf) {
        int n = w * 32 + cf * 16 + ln;
        float bv = bias1[n];
        #pragma unroll
        for (int rf = 0; rf < 4; ++rf)
            #pragma unroll
            for (int reg = 0; reg < 4; ++reg)
                ts[rf*16 + g*4 + reg][n] = (half_t)sspf(acc[rf][cf][reg] + bv);
    }
    __syncthreads();

    // layer 2
    f32x4 acc2[4][2];
    #pragma unroll
    for (int rf = 0; rf < 4; ++rf)
        #pragma unroll
        for (int cf = 0; cf < 2; ++cf) acc2[rf][cf] = (f32x4)0.f;
    #pragma unroll
    for (int kk = 0; kk < 8; ++kk) {
        const int kb = kk * 16 + g * 4;
        half4_t a[4];
        #pragma unroll
        for (int rf = 0; rf < 4; ++rf)
            a[rf] = *(const half4_t*)&ts[rf*16 + ln][kb];
        #pragma unroll
        for (int cf = 0; cf < 2; ++cf) {
            int n = w * 32 + cf * 16 + ln;
            half4_t b = *(const half4_t*)(Bt2 + (size_t)n * 128 + kb);
            #pragma unroll
            for (int rf = 0; rf < 4; ++rf)
                acc2[rf][cf] = __builtin_amdgcn_mfma_f32_16x16x16f16(a[rf], b, acc2[rf][cf], 0, 0, 0);
        }
    }
    #pragma unroll
    for (int cf = 0; cf < 2; ++cf) {
        int n = w * 32 + cf * 16 + ln;
        float bv = bias2[n];
        #pragma unroll
        for (int rf = 0; rf < 4; ++rf)
            #pragma unroll
            for (int reg = 0; reg < 4; ++reg) {
                int r = r0 + rf * 16 + g * 4 + reg;
                if (r < nrows) out[(size_t)r * 128 + n] = acc2[rf][cf][reg] + bv;
            }
    }
}

// Wave-independent edge pipeline. R15: h via DMA (proven 232 MB FETCH) but
// SINGLE-buffered hsh -> LDS 49.7 KB -> 3 blocks/CU (3 waves/SIMD, +50% TLP).
// DMA(k) issues at top of iter k (hsh freed by prev epilogue in program
// order); cover = prefetch + phase1 + softplus + phase2; vmcnt(4) retires it.
__global__ __launch_bounds__(256, 3) void edge_kernel(
    const float* __restrict__ f_ij, const float* __restrict__ rcut,
    const int* __restrict__ idx_j,
    const half_t* __restrict__ Wt_f1, const float* __restrict__ b1sc,
    const half_t* __restrict__ W2L, const float* __restrict__ b2a,
    const half_t* __restrict__ hh, float* __restrict__ agg,
    const int* __restrict__ atom_start, int E, int N, int W)
{
    __shared__ __align__(16) half_t W2s[16384];        // 32768 B
    __shared__ __align__(16) half_t hsh[4][2048];      // 16384 B (4KB per wave)
    __shared__ float b1s[128];                         //   512 B
    // 49664 B -> 3 blocks/CU

    const int tid = threadIdx.x;
    const int w = tid >> 6, l = tid & 63, g = l >> 4, ln = l & 15;

    for (int i = tid; i < 2048; i += 256)
        ((float4*)W2s)[i] = ((const float4*)W2L)[i];
    if (tid < 128) b1s[tid] = b1sc[tid];
    __syncthreads();

    // per-wave atom range (edge-balanced)
    const int kg = blockIdx.x * 4 + w;
    const int aLo = lbound(atom_start, N + 1, (int)((size_t)kg * E / W));
    const int aHi = (kg == W - 1) ? N
                  : lbound(atom_start, N + 1, (int)((size_t)(kg + 1) * E / W));
    if (aLo >= aHi) return;

    // W1 A-frags in VGPRs (x32 stacked-K)
    half8_t w1f[8];
    #pragma unroll
    for (int rf = 0; rf < 8; ++rf) {
        half4_t lo = *(const half4_t*)(Wt_f1 + (size_t)(rf*16 + ln)*32 + g*4);
        half4_t hi = *(const half4_t*)(Wt_f1 + (size_t)(rf*16 + ln)*32 + 16 + g*4);
        w1f[rf] = __builtin_shufflevector(lo, hi, 0, 1, 2, 3, 4, 5, 6, 7);
    }

    // persistent b2' accumulator seeds (lane cols = ln*8 .. ln*8+7)
    f32x4 b2acc[8];
    {
        float4 blo4 = *(const float4*)(b2a + ln*8);
        float4 bhi4 = *(const float4*)(b2a + ln*8 + 4);
        float bv[8] = {blo4.x, blo4.y, blo4.z, blo4.w, bhi4.x, bhi4.y, bhi4.z, bhi4.w};
        #pragma unroll
        for (int q = 0; q < 8; ++q) {
            f32x4 t = {bv[q], bv[q], bv[q], bv[q]};
            b2acc[q] = t;
        }
    }

    // atom window
    int acur = aLo;
    int ends0 = atom_start[acur + 1];
    int ends1 = atom_start[min(acur + 2, N)];
    int ends2 = atom_start[min(acur + 3, N)];
    int cs = atom_start[acur];

    // prologue: chunk-0 jv (DMA layout: row block it, my group g), f, rc
    int jv[4]; float4 fA, fB; float rc[4];
    #pragma unroll
    for (int it = 0; it < 4; ++it)
        jv[it] = idx_j[min(cs + 4*it + g, E - 1)];
    {
        int e = min(cs + ln, E - 1);
        fA = *(const float4*)(f_ij + (size_t)e*20 + g*4);
        fB = *(const float4*)(f_ij + (size_t)e*20 + 16);
    }
    #pragma unroll
    for (int r2 = 0; r2 < 4; ++r2) rc[r2] = rcut[min(cs + 4*g + r2, E - 1)];
    asm volatile("" ::: "memory");

    float racc[8];
    #pragma unroll
    for (int q = 0; q < 8; ++q) racc[q] = 0.f;

    while (acur < aHi) {
        const int ce = min(cs + 16, ends0);
        const int csn = ce;
        const bool flushF = (ce == ends0);

        // ---- 1: DMA(k) into hsh (freed by prev epilogue; 4 vmem ops) ----
        asm volatile("" ::: "memory");
        #pragma unroll
        for (int it = 0; it < 4; ++it)
            load_lds16(hh + (size_t)jv[it]*128 + ((ln ^ it) << 3),
                       &hsh[w][it*512]);
        asm volatile("" ::: "memory");

        // ---- 2: consume prefetched f/rc (no compiler re-waits later) ----
        half4_t blo = cvt4(fA.x, fA.y, fA.z, fA.w);
        half4_t bhi;
        if (g == 0) bhi = cvt4(fB.x, fB.y, fB.z, fB.w);
        else { half4_t zz = {}; bhi = zz; }
        half8_t bf = __builtin_shufflevector(blo, bhi, 0, 1, 2, 3, 4, 5, 6, 7);
        float rcm[4];
        #pragma unroll
        for (int r2 = 0; r2 < 4; ++r2)
            rcm[r2] = (cs + 4*g + r2 < ce) ? rc[r2] : 0.f;

        // ---- 3: prefetch NEXT chunk (jv/f/rc at csn) + atom window ----
        int jvn[4];
        #pragma unroll
        for (int it = 0; it < 4; ++it)
            jvn[it] = idx_j[min(csn + 4*it + g, E - 1)];
        float4 fA1, fB1;
        {
            int e = min(csn + ln, E - 1);
            fA1 = *(const float4*)(f_ij + (size_t)e*20 + g*4);
            fB1 = *(const float4*)(f_ij + (size_t)e*20 + 16);
        }
        float rc1[4];
        #pragma unroll
        for (int r2 = 0; r2 < 4; ++r2) rc1[r2] = rcut[min(csn + 4*g + r2, E - 1)];
        const int aeL = atom_start[min(acur + 4, N)];
        asm volatile("" ::: "memory");

        // ---- 4: phase 1 (K=32) + folded softplus: a2 = log2(1 + 2^u) ----
        f32x4 z[8];
        #pragma unroll
        for (int rf = 0; rf < 8; ++rf)
            z[rf] = __builtin_amdgcn_mfma_f32_16x16x32_f16(w1f[rf], bf, (f32x4)0.f, 0, 0, 0);
        half8_t a2[4];
        #pragma unroll
        for (int t = 0; t < 4; ++t) {
            float4 bbA = *(const float4*)&b1s[(2*t)*16 + g*4];
            float4 bbB = *(const float4*)&b1s[(2*t+1)*16 + g*4];
            float l0 = __log2f(1.f + exp2f(fmaf(z[2*t][0],   LOG2EF, bbA.x)));
            float l1 = __log2f(1.f + exp2f(fmaf(z[2*t][1],   LOG2EF, bbA.y)));
            float l2 = __log2f(1.f + exp2f(fmaf(z[2*t][2],   LOG2EF, bbA.z)));
            float l3 = __log2f(1.f + exp2f(fmaf(z[2*t][3],   LOG2EF, bbA.w)));
            float l4 = __log2f(1.f + exp2f(fmaf(z[2*t+1][0], LOG2EF, bbB.x)));
            float l5 = __log2f(1.f + exp2f(fmaf(z[2*t+1][1], LOG2EF, bbB.y)));
            float l6 = __log2f(1.f + exp2f(fmaf(z[2*t+1][2], LOG2EF, bbB.z)));
            float l7 = __log2f(1.f + exp2f(fmaf(z[2*t+1][3], LOG2EF, bbB.w)));
            a2[t] = pk8(l0, l1, l2, l3, l4, l5, l6, l7);
        }

        // ---- 5: phase 2 (32 MFMA), acc seeded from persistent b2acc ----
        f32x4 acc[8];
        #pragma unroll
        for (int q = 0; q < 8; ++q) acc[q] = b2acc[q];
        __builtin_amdgcn_s_setprio(1);
        #pragma unroll
        for (int t = 0; t < 4; ++t)
            #pragma unroll
            for (int q = 0; q < 8; ++q) {
                half8_t bw = *(const half8_t*)&W2s[(((t*8 + q)*4 + g)*16 + ln)*8];
                acc[q] = __builtin_amdgcn_mfma_f32_16x16x32_f16(a2[t], bw, acc[q], 0, 0, 0);
            }
        __builtin_amdgcn_s_setprio(0);

        // ---- 6: retire DMA(k): >=4 prefetch vmem are younger, DMAs oldest ----
        asm volatile("s_waitcnt vmcnt(4)" ::: "memory");
        __builtin_amdgcn_sched_barrier(0);

        // ---- 7: epilogue — 4x ds_read_b128 (cols ln*8..ln*8+7 per edge) ----
        #pragma unroll
        for (int r2 = 0; r2 < 4; ++r2) {
            half8_t hv8 = *(const half8_t*)&hsh[w][(4*g + r2)*128 + ((ln ^ g) << 3)];
            float rr = rcm[r2];
            #pragma unroll
            for (int q = 0; q < 8; ++q)
                racc[q] = fmaf(acc[q][r2] * rr, (float)hv8[q], racc[q]);
        }

        // ---- 8: atom flush (coalesced float4 stores) ----
        if (flushF) {
            #pragma unroll
            for (int q = 0; q < 8; ++q) {
                float r = racc[q];
                r += __shfl_xor(r, 16, 64);
                r += __shfl_xor(r, 32, 64);
                racc[q] = r;
            }
            if (g == 0) {
                float4 v0 = {racc[0], racc[1], racc[2], racc[3]};
                float4 v1 = {racc[4], racc[5], racc[6], racc[7]};
                *(float4*)(agg + (size_t)acur*128 + ln*8)     = v0;
                *(float4*)(agg + (size_t)acur*128 + ln*8 + 4) = v1;
            }
            #pragma unroll
            for (int q = 0; q < 8; ++q) racc[q] = 0.f;
            ++acur;
            ends0 = ends1; ends1 = ends2; ends2 = aeL;
        }

        // ---- 9: rotate pipeline state ----
        cs = csn;
        #pragma unroll
        for (int it = 0; it < 4; ++it) jv[it] = jvn[it];
        fA = fA1; fB = fB1;
        #pragma unroll
        for (int r2 = 0; r2 < 4; ++r2) rc[r2] = rc1[r2];
    }
}

extern "C" void kernel_launch(void* const* d_in, const int* in_sizes, int n_in,
                              void* d_out, int out_size, void* d_ws, size_t ws_size,
                              hipStream_t stream)
{
    const float* x      = (const float*)d_in[0];
    const float* f_ij   = (const float*)d_in[1];
    const float* rcut   = (const float*)d_in[2];
    const int*   idx_i  = (const int*)d_in[3];
    const int*   idx_j  = (const int*)d_in[4];
    const float* W_in2f = (const float*)d_in[5];
    const float* W_f1   = (const float*)d_in[6];
    const float* b_f1   = (const float*)d_in[7];
    const float* W_f2   = (const float*)d_in[8];
    const float* b_f2   = (const float*)d_in[9];
    const float* W_o1   = (const float*)d_in[10];
    const float* b_o1   = (const float*)d_in[11];
    const float* W_o2   = (const float*)d_in[12];
    const float* b_o2   = (const float*)d_in[13];

    const int N = in_sizes[0] / 128;
    const int E = in_sizes[2];

    half_t* h16  = (half_t*)d_ws;                       // [N,128] f16
    half_t* wt   = (half_t*)((char*)d_ws + (size_t)N * 128 * 4);
    half_t* Wt_in2f = wt;                 // 16384 halfs
    half_t* Wt_f1   = wt + 16384;         //  4096 (x32-padded [n][32])
    half_t* W2L     = wt + 16384 + 4096;  // 16384 (x32 stacked W_f2 * ln2)
    half_t* Wt_o1   = W2L + 16384;        // 16384
    half_t* Wt_o2   = Wt_o1 + 16384;      // 16384
    float*  b1sc    = (float*)(Wt_o2 + 16384);          // 128 floats
    float*  b2a     = b1sc + 128;                       // 128 floats
    int* atom_start = (int*)(b2a + 128);                // N+1 ints

    prep_weights<<<273, 256, 0, stream>>>(W_in2f, W_f1, W_f2, W_o1, W_o2,
                                          b_f1, b_f2,
                                          Wt_in2f, Wt_f1, W2L, Wt_o1, Wt_o2,
                                          b1sc, b2a);
    seg_starts<<<(E + 255) / 256, 256, 0, stream>>>(idx_i, atom_start, E, N);

    const int gn  = (N + 63) / 64;
    const int nbl = 768;                  // 4 waves/block, 3 blocks/CU, resident
    const int W   = nbl * 4;

    // h = x @ W_in2f -> f16
    mfma_gemm_h<<<gn, 256, 0, stream>>>(x, Wt_in2f, h16, N);

    // wave-independent fused edge pipeline -> agg (writes every atom row once)
    edge_kernel<<<nbl, 256, 0, stream>>>(f_ij, rcut, idx_j,
                                         Wt_f1, b1sc, W2L, b2a,
                                         h16, (float*)d_out, atom_start, E, N, W);

    // out = ssp(agg @ W_o1 + b_o1) @ W_o2 + b_o2   (fused, in-place on d_out)
    mfma_gemm2<<<gn, 256, 0, stream>>>((const float*)d_out, Wt_o1, b_o1,
                                       Wt_o2, b_o2, (float*)d_out, N);
}